// Round 1
// baseline (16360.793 us; speedup 1.0000x reference)
//
#include <hip/hip_runtime.h>

typedef short s16x8 __attribute__((ext_vector_type(8)));
typedef short s16x4 __attribute__((ext_vector_type(4)));
typedef float f32x4 __attribute__((ext_vector_type(4)));

#define T_N 2048
#define B_N 64
#define H_N 256
#define I_N 256
#define HY_BYTES ((size_t)134217728)   // 4 * T * B * H

static __device__ __forceinline__ short f2bf(float f) {
    unsigned u = __builtin_bit_cast(unsigned, f);
    u += 0x7FFFu + ((u >> 16) & 1u);   // RNE
    return (short)(u >> 16);
}
static __device__ __forceinline__ float bf2f(short h) {
    unsigned u = ((unsigned)(unsigned short)h) << 16;
    return __builtin_bit_cast(float, u);
}
static __device__ __forceinline__ float sigf(float x) {
    return 1.0f / (1.0f + __expf(-x));
}
static __device__ __forceinline__ float tanhf_fast(float x) {
    // 2/(1+exp(-2x)) - 1 : saturates correctly, no overflow
    return 2.0f / (1.0f + __expf(-2.0f * x)) - 1.0f;
}

// ---------------------------------------------------------------------------
// Phase 1: xg[t,b,n] = x[t,b,:] @ w_ih[n,:] + (b_ih[n]+b_hh[n]),  stored bf16
// in MFMA C-fragment layout inside d_out:
//   tile tau = n/16 (i:0-15, f:16-31 -> hy slot; g:32-47, o:48-63 -> cy slot)
//   slot(t,g) 16KB; value (lane l, reg r) at  base + tau'*512 + l*8 + r*2
// Grid (1024, 4), block 512.  Each wave: one 16-row M-tile x 256 cols.
// ---------------------------------------------------------------------------
__global__ __launch_bounds__(512) void xg_gemm(
        const float* __restrict__ x, const float* __restrict__ w_ih,
        const float* __restrict__ b_ih, const float* __restrict__ b_hh,
        char* __restrict__ out)
{
    const int tid  = threadIdx.x;
    const int wave = tid >> 6;
    const int lane = tid & 63;
    const int l15  = lane & 15;
    const int kg   = lane >> 4;

    __shared__ short Blds[8192];   // 16 tiles * 64 lanes * 8 bf16 = 16 KB

    const int m16 = blockIdx.x * 8 + wave;   // 16-row tile id [0,8192)
    const int by  = blockIdx.y;              // col block of 256
    const int n0  = by * 256;

    const float* xrow = x + (size_t)(m16 * 16 + l15) * I_N;

    f32x4 acc[16] = {};

#pragma unroll 1
    for (int ks = 0; ks < 8; ++ks) {
        __syncthreads();
        // stage B chunk: w_ih rows [n0,n0+256), k in [ks*32, ks*32+32)
#pragma unroll
        for (int h = 0; h < 2; ++h) {
            int nl = (tid >> 2) + h * 128;
            int c  = tid & 3;
            const float* wp = w_ih + (size_t)(n0 + nl) * I_N + ks * 32 + c * 8;
            f32x4 w0 = *(const f32x4*)(wp);
            f32x4 w1 = *(const f32x4*)(wp + 4);
            s16x8 bv;
            bv[0]=f2bf(w0[0]); bv[1]=f2bf(w0[1]); bv[2]=f2bf(w0[2]); bv[3]=f2bf(w0[3]);
            bv[4]=f2bf(w1[0]); bv[5]=f2bf(w1[1]); bv[6]=f2bf(w1[2]); bv[7]=f2bf(w1[3]);
            int dt = nl >> 4;
            int lp = (nl & 15) + 16 * c;
            *(s16x8*)(&Blds[(dt * 64 + lp) * 8]) = bv;
        }
        __syncthreads();
        const float* ap = xrow + ks * 32 + kg * 8;
        f32x4 a0 = *(const f32x4*)(ap);
        f32x4 a1 = *(const f32x4*)(ap + 4);
        s16x8 av;
        av[0]=f2bf(a0[0]); av[1]=f2bf(a0[1]); av[2]=f2bf(a0[2]); av[3]=f2bf(a0[3]);
        av[4]=f2bf(a1[0]); av[5]=f2bf(a1[1]); av[6]=f2bf(a1[2]); av[7]=f2bf(a1[3]);
#pragma unroll
        for (int dt = 0; dt < 16; ++dt) {
            s16x8 bv = *(const s16x8*)(&Blds[(dt * 64 + lane) * 8]);
            acc[dt] = __builtin_amdgcn_mfma_f32_16x16x32_bf16(av, bv, acc[dt], 0, 0, 0);
        }
    }

    const int t = m16 >> 2;
    const int g = m16 & 3;
#pragma unroll
    for (int dt = 0; dt < 16; ++dt) {
        int tau = by * 16 + dt;
        int n   = tau * 16 + l15;
        float bias = b_ih[n] + b_hh[n];
        size_t base = (tau < 32)
            ? ((size_t)t * 65536 + (size_t)g * 16384 + (size_t)tau * 512)
            : (HY_BYTES + (size_t)t * 65536 + (size_t)g * 16384 + (size_t)(tau - 32) * 512);
        s16x4 o;
        o[0] = f2bf(acc[dt][0] + bias);
        o[1] = f2bf(acc[dt][1] + bias);
        o[2] = f2bf(acc[dt][2] + bias);
        o[3] = f2bf(acc[dt][3] + bias);
        *(s16x4*)(out + base + lane * 8) = o;
    }
}

// ---------------------------------------------------------------------------
// Phase 2: persistent recurrence. 4 WGs (one per 16-batch group), 8 waves.
// Wave w owns h-cols [32w,32w+32) => gate tiles tau = 16q + 2w + ct.
// w_hh bf16 fragments: tiles d=0..5 (i,f,g) in 192 VGPRs, d=6,7 (o) in LDS.
// h state: bf16 in LDS (XOR-swizzled), c state: f32 in registers.
// Each step reads its xg slot from d_out and overwrites it with h,c (f32).
// ---------------------------------------------------------------------------
__global__ __launch_bounds__(512, 2) void lstm_rec(
        const float* __restrict__ h0, const float* __restrict__ c0,
        const float* __restrict__ w_hh, char* __restrict__ out)
{
    const int g    = blockIdx.x;
    const int tid  = threadIdx.x;
    const int w    = tid >> 6;
    const int lane = tid & 63;
    const int l15  = lane & 15;
    const int kg   = lane >> 4;

    __shared__ short hlds[4096];     // 16 x 256 bf16, swizzled  (8 KB)
    __shared__ short wlds[65536];    // 8 waves x 2 tiles x 8 ks x 64 x 8 (128 KB)

    // ---- W fragments ----
    s16x8 wreg[6][8];
#pragma unroll
    for (int d = 0; d < 8; ++d) {
        const int q = d >> 1, ct = d & 1;
        const int tau = 16 * q + 2 * w + ct;
        const float* wp = w_hh + (size_t)(tau * 16 + l15) * H_N;
#pragma unroll
        for (int ks = 0; ks < 8; ++ks) {
            const float* p = wp + ks * 32 + kg * 8;
            f32x4 w0 = *(const f32x4*)(p);
            f32x4 w1 = *(const f32x4*)(p + 4);
            s16x8 v;
            v[0]=f2bf(w0[0]); v[1]=f2bf(w0[1]); v[2]=f2bf(w0[2]); v[3]=f2bf(w0[3]);
            v[4]=f2bf(w1[0]); v[5]=f2bf(w1[1]); v[6]=f2bf(w1[2]); v[7]=f2bf(w1[3]);
            if (d < 6) {
                wreg[d][ks] = v;
            } else {
                *(s16x8*)(&wlds[(((w * 2 + (d - 6)) * 8 + ks) * 64 + lane) * 8]) = v;
            }
        }
    }

    // ---- h0 -> hlds (bf16, XOR swizzle per row) ----
    {
        const int row  = tid >> 5;
        const int col0 = (tid & 31) * 8;
        const float* hp = h0 + (size_t)(g * 16 + row) * H_N + col0;
        const int sw = (row & 7) << 4;
#pragma unroll
        for (int j = 0; j < 8; ++j) {
            int byte = row * 512 + ((2 * (col0 + j)) ^ sw);
            *(short*)((char*)hlds + byte) = f2bf(hp[j]);
        }
    }

    // ---- c0 -> registers ----
    float cst[2][4];
#pragma unroll
    for (int ct = 0; ct < 2; ++ct)
#pragma unroll
        for (int r = 0; r < 4; ++r)
            cst[ct][r] = c0[(size_t)(g * 16 + kg * 4 + r) * H_N + 32 * w + 16 * ct + l15];

    float hnew[2][4] = {};

    __syncthreads();

    const int amask = (l15 & 7) << 4;
    size_t t_off = 0;
#pragma unroll 1
    for (int t = 0; t < T_N; ++t, t_off += 65536) {
        // xg loads (issued early; values are this step's slot, pre-overwrite)
        s16x4 xg[8];
#pragma unroll
        for (int d = 0; d < 8; ++d) {
            const int q = d >> 1, ct = d & 1;
            const int tau = 16 * q + 2 * w + ct;
            size_t off = (q < 2)
                ? (t_off + (size_t)g * 16384 + (size_t)tau * 512)
                : (HY_BYTES + t_off + (size_t)g * 16384 + (size_t)(tau - 32) * 512);
            xg[d] = *(const s16x4*)(out + off + lane * 8);
        }

        // gates_acc = h_{t-1} @ w_hh^T
        f32x4 acc[8] = {};
#pragma unroll
        for (int ks = 0; ks < 8; ++ks) {
            s16x8 av = *(const s16x8*)((const char*)hlds +
                            l15 * 512 + ((ks * 64 + kg * 16) ^ amask));
#pragma unroll
            for (int d = 0; d < 6; ++d)
                acc[d] = __builtin_amdgcn_mfma_f32_16x16x32_bf16(av, wreg[d][ks], acc[d], 0, 0, 0);
#pragma unroll
            for (int d2 = 0; d2 < 2; ++d2) {
                s16x8 bv = *(const s16x8*)(&wlds[(((w * 2 + d2) * 8 + ks) * 64 + lane) * 8]);
                acc[6 + d2] = __builtin_amdgcn_mfma_f32_16x16x32_bf16(av, bv, acc[6 + d2], 0, 0, 0);
            }
        }

        // activations + state update
#pragma unroll
        for (int ct = 0; ct < 2; ++ct) {
#pragma unroll
            for (int r = 0; r < 4; ++r) {
                float gi = sigf(acc[0 + ct][r] + bf2f(xg[0 + ct][r]));
                float gf = sigf(acc[2 + ct][r] + bf2f(xg[2 + ct][r]));
                float gg = tanhf_fast(acc[4 + ct][r] + bf2f(xg[4 + ct][r]));
                float go = sigf(acc[6 + ct][r] + bf2f(xg[6 + ct][r]));
                float c  = gf * cst[ct][r] + gi * gg;
                cst[ct][r]  = c;
                hnew[ct][r] = go * tanhf_fast(c);
            }
        }

        __syncthreads();   // all waves done reading hlds + this step's xg slots

        // h -> hlds (bf16, swizzled)
#pragma unroll
        for (int ct = 0; ct < 2; ++ct)
#pragma unroll
            for (int r = 0; r < 4; ++r) {
                int row = kg * 4 + r;
                int col = 32 * w + 16 * ct + l15;
                int byte = row * 512 + ((2 * col) ^ ((row & 7) << 4));
                *(short*)((char*)hlds + byte) = f2bf(hnew[ct][r]);
            }

        // h, c -> global f32 (overwrites this step's xg slots; WG-private)
        {
            char* hyp = out + t_off;
            char* cyp = out + HY_BYTES + t_off;
#pragma unroll
            for (int ct = 0; ct < 2; ++ct)
#pragma unroll
                for (int r = 0; r < 4; ++r) {
                    size_t off = (size_t)(g * 16 + kg * 4 + r) * 1024 +
                                 (size_t)(32 * w + 16 * ct + l15) * 4;
                    *(float*)(hyp + off) = hnew[ct][r];
                    *(float*)(cyp + off) = cst[ct][r];
                }
        }

        __syncthreads();   // hlds ready for next step
    }

    // final (hy[-1], cy[-1])
    {
        char* hf = out + 2 * HY_BYTES;
        char* cf = out + 2 * HY_BYTES + 65536;
#pragma unroll
        for (int ct = 0; ct < 2; ++ct)
#pragma unroll
            for (int r = 0; r < 4; ++r) {
                size_t off = (size_t)(g * 16 + kg * 4 + r) * 1024 +
                             (size_t)(32 * w + 16 * ct + l15) * 4;
                *(float*)(hf + off) = hnew[ct][r];
                *(float*)(cf + off) = cst[ct][r];
            }
    }
}

extern "C" void kernel_launch(void* const* d_in, const int* in_sizes, int n_in,
                              void* d_out, int out_size, void* d_ws, size_t ws_size,
                              hipStream_t stream) {
    (void)in_sizes; (void)n_in; (void)out_size; (void)d_ws; (void)ws_size;
    const float* x    = (const float*)d_in[0];
    const float* h0   = (const float*)d_in[1];
    const float* c0   = (const float*)d_in[2];
    const float* w_ih = (const float*)d_in[3];
    const float* w_hh = (const float*)d_in[4];
    const float* b_ih = (const float*)d_in[5];
    const float* b_hh = (const float*)d_in[6];
    char* out = (char*)d_out;

    xg_gemm<<<dim3(1024, 4), 512, 0, stream>>>(x, w_ih, b_ih, b_hh, out);
    lstm_rec<<<4, 512, 0, stream>>>(h0, c0, w_hh, out);
}

// Round 2
// 13497.340 us; speedup vs baseline: 1.2121x; 1.2121x over previous
//
#include <hip/hip_runtime.h>

typedef short s16x8 __attribute__((ext_vector_type(8)));
typedef short s16x4 __attribute__((ext_vector_type(4)));
typedef float f32x4 __attribute__((ext_vector_type(4)));

#define T_N 2048
#define B_N 64
#define H_N 256
#define I_N 256
#define HY_BYTES ((size_t)134217728)   // 4 * T * B * H

static __device__ __forceinline__ short f2bf(float f) {
    unsigned u = __builtin_bit_cast(unsigned, f);
    u += 0x7FFFu + ((u >> 16) & 1u);   // RNE
    return (short)(u >> 16);
}
static __device__ __forceinline__ float bf2f(short h) {
    unsigned u = ((unsigned)(unsigned short)h) << 16;
    return __builtin_bit_cast(float, u);
}
static __device__ __forceinline__ float e2c(float a) {
    // exp2 with overflow clamp (keeps paired-rcp NaN-free under saturation)
    return __builtin_amdgcn_exp2f(fminf(a, 126.0f));
}

#define C1 1.44269504088896340f   // log2(e)
#define C2 2.88539008177792681f   // 2*log2(e)

// ---------------------------------------------------------------------------
// Phase 1: xg[t,b,n] = x[t,b,:] @ w_ih[n,:] + (b_ih[n]+b_hh[n]),  stored bf16
// in MFMA C-fragment layout inside d_out (unchanged from round 1).
// ---------------------------------------------------------------------------
__global__ __launch_bounds__(512) void xg_gemm(
        const float* __restrict__ x, const float* __restrict__ w_ih,
        const float* __restrict__ b_ih, const float* __restrict__ b_hh,
        char* __restrict__ out)
{
    const int tid  = threadIdx.x;
    const int wave = tid >> 6;
    const int lane = tid & 63;
    const int l15  = lane & 15;
    const int kg   = lane >> 4;

    __shared__ short Blds[8192];

    const int m16 = blockIdx.x * 8 + wave;
    const int by  = blockIdx.y;
    const int n0  = by * 256;

    const float* xrow = x + (size_t)(m16 * 16 + l15) * I_N;

    f32x4 acc[16] = {};

#pragma unroll 1
    for (int ks = 0; ks < 8; ++ks) {
        __syncthreads();
#pragma unroll
        for (int h = 0; h < 2; ++h) {
            int nl = (tid >> 2) + h * 128;
            int c  = tid & 3;
            const float* wp = w_ih + (size_t)(n0 + nl) * I_N + ks * 32 + c * 8;
            f32x4 w0 = *(const f32x4*)(wp);
            f32x4 w1 = *(const f32x4*)(wp + 4);
            s16x8 bv;
            bv[0]=f2bf(w0[0]); bv[1]=f2bf(w0[1]); bv[2]=f2bf(w0[2]); bv[3]=f2bf(w0[3]);
            bv[4]=f2bf(w1[0]); bv[5]=f2bf(w1[1]); bv[6]=f2bf(w1[2]); bv[7]=f2bf(w1[3]);
            int dt = nl >> 4;
            int lp = (nl & 15) + 16 * c;
            *(s16x8*)(&Blds[(dt * 64 + lp) * 8]) = bv;
        }
        __syncthreads();
        const float* ap = xrow + ks * 32 + kg * 8;
        f32x4 a0 = *(const f32x4*)(ap);
        f32x4 a1 = *(const f32x4*)(ap + 4);
        s16x8 av;
        av[0]=f2bf(a0[0]); av[1]=f2bf(a0[1]); av[2]=f2bf(a0[2]); av[3]=f2bf(a0[3]);
        av[4]=f2bf(a1[0]); av[5]=f2bf(a1[1]); av[6]=f2bf(a1[2]); av[7]=f2bf(a1[3]);
#pragma unroll
        for (int dt = 0; dt < 16; ++dt) {
            s16x8 bv = *(const s16x8*)(&Blds[(dt * 64 + lane) * 8]);
            acc[dt] = __builtin_amdgcn_mfma_f32_16x16x32_bf16(av, bv, acc[dt], 0, 0, 0);
        }
    }

    const int t = m16 >> 2;
    const int g = m16 & 3;
#pragma unroll
    for (int dt = 0; dt < 16; ++dt) {
        int tau = by * 16 + dt;
        int n   = tau * 16 + l15;
        float bias = b_ih[n] + b_hh[n];
        size_t base = (tau < 32)
            ? ((size_t)t * 65536 + (size_t)g * 16384 + (size_t)tau * 512)
            : (HY_BYTES + (size_t)t * 65536 + (size_t)g * 16384 + (size_t)(tau - 32) * 512);
        s16x4 o;
        o[0] = f2bf(acc[dt][0] + bias);
        o[1] = f2bf(acc[dt][1] + bias);
        o[2] = f2bf(acc[dt][2] + bias);
        o[3] = f2bf(acc[dt][3] + bias);
        *(s16x4*)(out + base + lane * 8) = o;
    }
}

// ---------------------------------------------------------------------------
// Phase 2: persistent recurrence. 4 WGs x 8 waves.
// W sourcing (fits 256 reg/wave): d=0..3 (i,f) in 128 VGPRs; d=4,5 (g) in
// 128KB LDS; d=6,7 (o) packed bf16 into d_ws, streamed from L2 each step.
// Activations: exp2/rcp intrinsics, paired reciprocals.
// Barriers: raw s_barrier; only lgkmcnt(0) drain (no vmcnt store drain).
// ---------------------------------------------------------------------------
template<bool USE_WS>
__global__ __launch_bounds__(512, 2) void lstm_rec(
        const float* __restrict__ h0, const float* __restrict__ c0,
        const float* __restrict__ w_hh, char* __restrict__ out,
        char* __restrict__ ws)
{
    const int g    = blockIdx.x;
    const int tid  = threadIdx.x;
    const int w    = tid >> 6;
    const int lane = tid & 63;
    const int l15  = lane & 15;
    const int kg   = lane >> 4;

    __shared__ short hlds[4096];     // 16 x 256 bf16, swizzled  (8 KB)
    __shared__ short wlds[65536];    // g-gate: 8 waves x 2 tiles x 8 ks x 64 x 8 (128 KB)

    s16x8 wreg[4][8];       // i,f gates
    s16x8 wregO[2][8];      // o gates (fallback only; DCE'd when USE_WS)

#pragma unroll
    for (int d = 0; d < 8; ++d) {
        const int q = d >> 1, ct = d & 1;
        const int tau = 16 * q + 2 * w + ct;
        const float* wp = w_hh + (size_t)(tau * 16 + l15) * H_N;
#pragma unroll
        for (int ks = 0; ks < 8; ++ks) {
            const float* p = wp + ks * 32 + kg * 8;
            f32x4 w0 = *(const f32x4*)(p);
            f32x4 w1 = *(const f32x4*)(p + 4);
            s16x8 v;
            v[0]=f2bf(w0[0]); v[1]=f2bf(w0[1]); v[2]=f2bf(w0[2]); v[3]=f2bf(w0[3]);
            v[4]=f2bf(w1[0]); v[5]=f2bf(w1[1]); v[6]=f2bf(w1[2]); v[7]=f2bf(w1[3]);
            if (d < 4) {
                wreg[d][ks] = v;
            } else if (d < 6) {
                *(s16x8*)(&wlds[(((w * 2 + (d - 4)) * 8 + ks) * 64 + lane) * 8]) = v;
            } else {
                if constexpr (USE_WS) {
                    *(s16x8*)(ws + (size_t)(((w * 2 + (d - 6)) * 8 + ks) * 64 + lane) * 16) = v;
                } else {
                    wregO[d - 6][ks] = v;
                }
            }
        }
    }
    if constexpr (USE_WS) {
        // own stores acked at L2 before in-loop reads (same wave, same L2)
        asm volatile("s_waitcnt vmcnt(0)" ::: "memory");
    }

    // ---- h0 -> hlds (bf16, XOR swizzle per row) ----
    {
        const int row  = tid >> 5;
        const int col0 = (tid & 31) * 8;
        const float* hp = h0 + (size_t)(g * 16 + row) * H_N + col0;
        const int sw = (row & 7) << 4;
#pragma unroll
        for (int j = 0; j < 8; ++j) {
            int byte = row * 512 + ((2 * (col0 + j)) ^ sw);
            *(short*)((char*)hlds + byte) = f2bf(hp[j]);
        }
    }

    // ---- c0 -> registers ----
    float cst[2][4];
#pragma unroll
    for (int ct = 0; ct < 2; ++ct)
#pragma unroll
        for (int r = 0; r < 4; ++r)
            cst[ct][r] = c0[(size_t)(g * 16 + kg * 4 + r) * H_N + 32 * w + 16 * ct + l15];

    float hnew[2][4] = {};

    __syncthreads();

    // loop-invariant / strength-reduced pointers
    const char* p_i = out + (size_t)g * 16384 + (size_t)w * 1024 + (size_t)lane * 8;
    const char* p_f = p_i + 8192;
    const char* p_g = out + HY_BYTES + (size_t)g * 16384 + (size_t)w * 1024 + (size_t)lane * 8;
    const char* p_o = p_g + 8192;
    char* st_h = out + (size_t)(g * 16 + kg * 4) * 1024 + (size_t)(32 * w + l15) * 4;
    char* st_c = st_h + HY_BYTES;

    const int amask = (l15 & 7) << 4;

#pragma unroll 1
    for (int t = 0; t < T_N; ++t) {
        // xg loads for this step (slot overwritten only after barrier 1)
        s16x4 xg[8];
        xg[0] = *(const s16x4*)(p_i);
        xg[1] = *(const s16x4*)(p_i + 512);
        xg[2] = *(const s16x4*)(p_f);
        xg[3] = *(const s16x4*)(p_f + 512);
        xg[4] = *(const s16x4*)(p_g);
        xg[5] = *(const s16x4*)(p_g + 512);
        xg[6] = *(const s16x4*)(p_o);
        xg[7] = *(const s16x4*)(p_o + 512);

        // gates_acc = h_{t-1} @ w_hh^T
        f32x4 acc[8] = {};
#pragma unroll
        for (int ks = 0; ks < 8; ++ks) {
            s16x8 av = *(const s16x8*)((const char*)hlds +
                            l15 * 512 + ((ks * 64 + kg * 16) ^ amask));
            acc[0] = __builtin_amdgcn_mfma_f32_16x16x32_bf16(av, wreg[0][ks], acc[0], 0, 0, 0);
            acc[1] = __builtin_amdgcn_mfma_f32_16x16x32_bf16(av, wreg[1][ks], acc[1], 0, 0, 0);
            acc[2] = __builtin_amdgcn_mfma_f32_16x16x32_bf16(av, wreg[2][ks], acc[2], 0, 0, 0);
            acc[3] = __builtin_amdgcn_mfma_f32_16x16x32_bf16(av, wreg[3][ks], acc[3], 0, 0, 0);
            s16x8 b4 = *(const s16x8*)(&wlds[(((w * 2 + 0) * 8 + ks) * 64 + lane) * 8]);
            acc[4] = __builtin_amdgcn_mfma_f32_16x16x32_bf16(av, b4, acc[4], 0, 0, 0);
            s16x8 b5 = *(const s16x8*)(&wlds[(((w * 2 + 1) * 8 + ks) * 64 + lane) * 8]);
            acc[5] = __builtin_amdgcn_mfma_f32_16x16x32_bf16(av, b5, acc[5], 0, 0, 0);
            s16x8 b6, b7;
            if constexpr (USE_WS) {
                b6 = *(const s16x8*)(ws + (size_t)(((w * 2 + 0) * 8 + ks) * 64 + lane) * 16);
                b7 = *(const s16x8*)(ws + (size_t)(((w * 2 + 1) * 8 + ks) * 64 + lane) * 16);
            } else {
                b6 = wregO[0][ks];
                b7 = wregO[1][ks];
            }
            acc[6] = __builtin_amdgcn_mfma_f32_16x16x32_bf16(av, b6, acc[6], 0, 0, 0);
            acc[7] = __builtin_amdgcn_mfma_f32_16x16x32_bf16(av, b7, acc[7], 0, 0, 0);
        }

        // activations + state update (exp2/rcp, paired reciprocals)
#pragma unroll
        for (int ct = 0; ct < 2; ++ct) {
#pragma unroll
            for (int r = 0; r < 4; ++r) {
                float zi = acc[0 + ct][r] + bf2f(xg[0 + ct][r]);
                float zf = acc[2 + ct][r] + bf2f(xg[2 + ct][r]);
                float zg = acc[4 + ct][r] + bf2f(xg[4 + ct][r]);
                float zo = acc[6 + ct][r] + bf2f(xg[6 + ct][r]);
                float Ei = e2c(-C1 * zi);
                float Ef = e2c(-C1 * zf);
                float Eg = e2c(-C2 * zg);
                float Eo = e2c(-C1 * zo);
                float ai = 1.0f + Ei, af = 1.0f + Ef;
                float ag = 1.0f + Eg, ao = 1.0f + Eo;
                float r1 = __builtin_amdgcn_rcpf(ai * af);
                float gi = r1 * af;
                float gf = r1 * ai;
                float r2 = __builtin_amdgcn_rcpf(ag * ao);
                float go = r2 * ag;
                float tg = 2.0f * (r2 * ao) - 1.0f;   // tanh(zg)
                float c  = gf * cst[ct][r] + gi * tg;
                cst[ct][r] = c;
                float Ec = e2c(-C2 * c);
                float tc = 2.0f * __builtin_amdgcn_rcpf(1.0f + Ec) - 1.0f;  // tanh(c)
                hnew[ct][r] = go * tc;
            }
        }

        // barrier 1: all waves consumed this step's hlds reads + xg loads
        asm volatile("" ::: "memory");
        __builtin_amdgcn_s_barrier();
        asm volatile("" ::: "memory");

        // h -> hlds (bf16, swizzled)
#pragma unroll
        for (int ct = 0; ct < 2; ++ct)
#pragma unroll
            for (int r = 0; r < 4; ++r) {
                int row = kg * 4 + r;
                int col = 32 * w + 16 * ct + l15;
                int byte = row * 512 + ((2 * col) ^ ((row & 7) << 4));
                *(short*)((char*)hlds + byte) = f2bf(hnew[ct][r]);
            }

        // h, c -> global f32 (overwrites this step's xg slots; ordered by barrier 1)
#pragma unroll
        for (int ct = 0; ct < 2; ++ct)
#pragma unroll
            for (int r = 0; r < 4; ++r) {
                *(float*)(st_h + r * 1024 + ct * 64) = hnew[ct][r];
                *(float*)(st_c + r * 1024 + ct * 64) = cst[ct][r];
            }

        // barrier 2: hlds writes visible; no vmcnt drain
        asm volatile("s_waitcnt lgkmcnt(0)" ::: "memory");
        __builtin_amdgcn_s_barrier();
        asm volatile("" ::: "memory");

        p_i += 65536; p_f += 65536; p_g += 65536; p_o += 65536;
        st_h += 65536; st_c += 65536;
    }

    // final (hy[-1], cy[-1])
    {
        char* fh = out + 2 * HY_BYTES + (size_t)(g * 16 + kg * 4) * 1024 + (size_t)(32 * w + l15) * 4;
        char* fc = fh + 65536;
#pragma unroll
        for (int ct = 0; ct < 2; ++ct)
#pragma unroll
            for (int r = 0; r < 4; ++r) {
                *(float*)(fh + r * 1024 + ct * 64) = hnew[ct][r];
                *(float*)(fc + r * 1024 + ct * 64) = cst[ct][r];
            }
    }
}

extern "C" void kernel_launch(void* const* d_in, const int* in_sizes, int n_in,
                              void* d_out, int out_size, void* d_ws, size_t ws_size,
                              hipStream_t stream) {
    (void)in_sizes; (void)n_in; (void)out_size;
    const float* x    = (const float*)d_in[0];
    const float* h0   = (const float*)d_in[1];
    const float* c0   = (const float*)d_in[2];
    const float* w_ih = (const float*)d_in[3];
    const float* w_hh = (const float*)d_in[4];
    const float* b_ih = (const float*)d_in[5];
    const float* b_hh = (const float*)d_in[6];
    char* out = (char*)d_out;

    xg_gemm<<<dim3(1024, 4), 512, 0, stream>>>(x, w_ih, b_ih, b_hh, out);
    if (ws_size >= 131072) {
        lstm_rec<true><<<4, 512, 0, stream>>>(h0, c0, w_hh, out, (char*)d_ws);
    } else {
        lstm_rec<false><<<4, 512, 0, stream>>>(h0, c0, w_hh, out, (char*)d_ws);
    }
}

// Round 3
// 11958.306 us; speedup vs baseline: 1.3682x; 1.1287x over previous
//
#include <hip/hip_runtime.h>

typedef short s16x8 __attribute__((ext_vector_type(8)));
typedef short s16x4 __attribute__((ext_vector_type(4)));
typedef float f32x4 __attribute__((ext_vector_type(4)));

#define T_N 2048
#define B_N 64
#define H_N 256
#define I_N 256
#define HY_BYTES ((size_t)134217728)   // 4 * T * B * H

static __device__ __forceinline__ short f2bf(float f) {
    unsigned u = __builtin_bit_cast(unsigned, f);
    u += 0x7FFFu + ((u >> 16) & 1u);   // RNE
    return (short)(u >> 16);
}
static __device__ __forceinline__ float bf2f(short h) {
    unsigned u = ((unsigned)(unsigned short)h) << 16;
    return __builtin_bit_cast(float, u);
}
static __device__ __forceinline__ float e2c(float a) {
    return __builtin_amdgcn_exp2f(fminf(a, 126.0f));
}
static __device__ __forceinline__ s16x4 ntl4(const void* p) {
    return __builtin_nontemporal_load((const s16x4*)p);
}
static __device__ __forceinline__ void ntsf(void* p, float v) {
    __builtin_nontemporal_store(v, (float*)p);
}

#define C1 1.44269504088896340f   // log2(e)
#define C2 2.88539008177792681f   // 2*log2(e)

#define MFMA(a, b, c) __builtin_amdgcn_mfma_f32_16x16x32_bf16(a, b, c, 0, 0, 0)

// ---------------------------------------------------------------------------
// Phase 1: xg[t,b,n] = x[t,b,:] @ w_ih[n,:] + (b_ih[n]+b_hh[n]),  bf16 in
// MFMA C-fragment layout inside d_out (unchanged).
// ---------------------------------------------------------------------------
__global__ __launch_bounds__(512) void xg_gemm(
        const float* __restrict__ x, const float* __restrict__ w_ih,
        const float* __restrict__ b_ih, const float* __restrict__ b_hh,
        char* __restrict__ out)
{
    const int tid  = threadIdx.x;
    const int wave = tid >> 6;
    const int lane = tid & 63;
    const int l15  = lane & 15;
    const int kg   = lane >> 4;

    __shared__ short Blds[8192];

    const int m16 = blockIdx.x * 8 + wave;
    const int by  = blockIdx.y;
    const int n0  = by * 256;

    const float* xrow = x + (size_t)(m16 * 16 + l15) * I_N;

    f32x4 acc[16] = {};

#pragma unroll 1
    for (int ks = 0; ks < 8; ++ks) {
        __syncthreads();
#pragma unroll
        for (int h = 0; h < 2; ++h) {
            int nl = (tid >> 2) + h * 128;
            int c  = tid & 3;
            const float* wp = w_ih + (size_t)(n0 + nl) * I_N + ks * 32 + c * 8;
            f32x4 w0 = *(const f32x4*)(wp);
            f32x4 w1 = *(const f32x4*)(wp + 4);
            s16x8 bv;
            bv[0]=f2bf(w0[0]); bv[1]=f2bf(w0[1]); bv[2]=f2bf(w0[2]); bv[3]=f2bf(w0[3]);
            bv[4]=f2bf(w1[0]); bv[5]=f2bf(w1[1]); bv[6]=f2bf(w1[2]); bv[7]=f2bf(w1[3]);
            int dt = nl >> 4;
            int lp = (nl & 15) + 16 * c;
            *(s16x8*)(&Blds[(dt * 64 + lp) * 8]) = bv;
        }
        __syncthreads();
        const float* ap = xrow + ks * 32 + kg * 8;
        f32x4 a0 = *(const f32x4*)(ap);
        f32x4 a1 = *(const f32x4*)(ap + 4);
        s16x8 av;
        av[0]=f2bf(a0[0]); av[1]=f2bf(a0[1]); av[2]=f2bf(a0[2]); av[3]=f2bf(a0[3]);
        av[4]=f2bf(a1[0]); av[5]=f2bf(a1[1]); av[6]=f2bf(a1[2]); av[7]=f2bf(a1[3]);
#pragma unroll
        for (int dt = 0; dt < 16; ++dt) {
            s16x8 bv = *(const s16x8*)(&Blds[(dt * 64 + lane) * 8]);
            acc[dt] = MFMA(av, bv, acc[dt]);
        }
    }

    const int t = m16 >> 2;
    const int g = m16 & 3;
#pragma unroll
    for (int dt = 0; dt < 16; ++dt) {
        int tau = by * 16 + dt;
        int n   = tau * 16 + l15;
        float bias = b_ih[n] + b_hh[n];
        size_t base = (tau < 32)
            ? ((size_t)t * 65536 + (size_t)g * 16384 + (size_t)tau * 512)
            : (HY_BYTES + (size_t)t * 65536 + (size_t)g * 16384 + (size_t)(tau - 32) * 512);
        s16x4 o;
        o[0] = f2bf(acc[dt][0] + bias);
        o[1] = f2bf(acc[dt][1] + bias);
        o[2] = f2bf(acc[dt][2] + bias);
        o[3] = f2bf(acc[dt][3] + bias);
        *(s16x4*)(out + base + lane * 8) = o;
    }
}

// ---------------------------------------------------------------------------
// Phase 2: persistent recurrence, 4 WGs x 8 waves, one barrier per step.
//  - xg double-buffered in regs, prefetched one full step ahead (HBM hidden)
//  - o-gate weights streamed from ws (L2) with 2-deep ks ring prefetch
//  - hlds double-buffered -> single s_barrier per step (lgkm drain only;
//    vmcnt(0) covers prefetch loads, h/c stores get a full step to retire)
// ---------------------------------------------------------------------------
template<bool USE_WS>
__global__ __launch_bounds__(512, 2) void lstm_rec(
        const float* __restrict__ h0, const float* __restrict__ c0,
        const float* __restrict__ w_hh, char* __restrict__ out,
        char* __restrict__ ws)
{
    const int g    = blockIdx.x;
    const int tid  = threadIdx.x;
    const int w    = tid >> 6;
    const int lane = tid & 63;
    const int l15  = lane & 15;
    const int kg   = lane >> 4;

    __shared__ short hlds[2][4096];  // double-buffered 16x256 bf16, swizzled (16 KB)
    __shared__ short wlds[65536];    // g-gate weights (128 KB)

    s16x8 wreg[4][8];       // i,f gates in VGPRs
    s16x8 wregO[2][8];      // o gates (fallback only; DCE'd when USE_WS)

#pragma unroll
    for (int d = 0; d < 8; ++d) {
        const int q = d >> 1, ct = d & 1;
        const int tau = 16 * q + 2 * w + ct;
        const float* wp = w_hh + (size_t)(tau * 16 + l15) * H_N;
#pragma unroll
        for (int ks = 0; ks < 8; ++ks) {
            const float* p = wp + ks * 32 + kg * 8;
            f32x4 w0 = *(const f32x4*)(p);
            f32x4 w1 = *(const f32x4*)(p + 4);
            s16x8 v;
            v[0]=f2bf(w0[0]); v[1]=f2bf(w0[1]); v[2]=f2bf(w0[2]); v[3]=f2bf(w0[3]);
            v[4]=f2bf(w1[0]); v[5]=f2bf(w1[1]); v[6]=f2bf(w1[2]); v[7]=f2bf(w1[3]);
            if (d < 4) {
                wreg[d][ks] = v;
            } else if (d < 6) {
                *(s16x8*)(&wlds[(((w * 2 + (d - 4)) * 8 + ks) * 64 + lane) * 8]) = v;
            } else {
                if constexpr (USE_WS) {
                    *(s16x8*)(ws + (size_t)(((w * 2 + (d - 6)) * 8 + ks) * 64 + lane) * 16) = v;
                } else {
                    wregO[d - 6][ks] = v;
                }
            }
        }
    }
    if constexpr (USE_WS) {
        asm volatile("s_waitcnt vmcnt(0)" ::: "memory");
    }

    // ---- h0 -> hlds[0] (bf16, XOR swizzle per row) ----
    {
        const int row  = tid >> 5;
        const int col0 = (tid & 31) * 8;
        const float* hp = h0 + (size_t)(g * 16 + row) * H_N + col0;
        const int sw = (row & 7) << 4;
#pragma unroll
        for (int j = 0; j < 8; ++j) {
            int byte = row * 512 + ((2 * (col0 + j)) ^ sw);
            *(short*)((char*)hlds[0] + byte) = f2bf(hp[j]);
        }
    }

    // ---- c0 -> registers ----
    float cst[2][4];
#pragma unroll
    for (int ct = 0; ct < 2; ++ct)
#pragma unroll
        for (int r = 0; r < 4; ++r)
            cst[ct][r] = c0[(size_t)(g * 16 + kg * 4 + r) * H_N + 32 * w + 16 * ct + l15];

    float hnew[2][4] = {};

    __syncthreads();

    const char* pxg  = out + (size_t)g * 16384 + (size_t)w * 1024 + (size_t)lane * 8;
    char* st_h = out + (size_t)(g * 16 + kg * 4) * 1024 + (size_t)(32 * w + l15) * 4;
    char* st_c = st_h + HY_BYTES;
    const char* wsb = ws + (size_t)w * 16384 + (size_t)lane * 16;

    const int amask = (l15 & 7) << 4;

    s16x4 xgA[8], xgB[8];

#define XG_LOAD(dst, T) do {                                                  \
        const char* _p = pxg + ((size_t)(T) << 16);                           \
        dst[0] = ntl4(_p);                   dst[1] = ntl4(_p + 512);         \
        dst[2] = ntl4(_p + 8192);            dst[3] = ntl4(_p + 8704);        \
        dst[4] = ntl4(_p + HY_BYTES);        dst[5] = ntl4(_p + HY_BYTES + 512); \
        dst[6] = ntl4(_p + HY_BYTES + 8192); dst[7] = ntl4(_p + HY_BYTES + 8704); \
    } while (0)

    XG_LOAD(xgA, 0);   // prologue: xg for step 0

#define STEP(XGC, XGN, PAR, T) do {                                           \
        /* h,c of step T-1 -> global (slot T-1; ordered by prior barriers) */ \
        if ((T) > 0) {                                                        \
            char* _hp = st_h + ((size_t)((T) - 1) << 16);                     \
            char* _cp = st_c + ((size_t)((T) - 1) << 16);                     \
            _Pragma("unroll")                                                 \
            for (int ct = 0; ct < 2; ++ct)                                    \
                _Pragma("unroll")                                             \
                for (int r = 0; r < 4; ++r) {                                 \
                    ntsf(_hp + r * 1024 + ct * 64, hnew[ct][r]);              \
                    ntsf(_cp + r * 1024 + ct * 64, cst[ct][r]);               \
                }                                                             \
        }                                                                     \
        /* prefetch next step's xg (HBM latency hidden under this step) */    \
        if ((T) + 1 < T_N) XG_LOAD(XGN, (T) + 1);                             \
        f32x4 acc[8] = {};                                                    \
        s16x8 bo[2][2];                                                       \
        if constexpr (USE_WS) {                                               \
            bo[0][0] = *(const s16x8*)(wsb + 0 * 8192 + 0 * 1024);            \
            bo[0][1] = *(const s16x8*)(wsb + 1 * 8192 + 0 * 1024);            \
            bo[1][0] = *(const s16x8*)(wsb + 0 * 8192 + 1 * 1024);            \
            bo[1][1] = *(const s16x8*)(wsb + 1 * 8192 + 1 * 1024);            \
        }                                                                     \
        _Pragma("unroll")                                                     \
        for (int ks = 0; ks < 8; ++ks) {                                      \
            s16x8 av = *(const s16x8*)((const char*)hlds[PAR] +               \
                            l15 * 512 + ((ks * 64 + kg * 16) ^ amask));       \
            acc[0] = MFMA(av, wreg[0][ks], acc[0]);                           \
            acc[1] = MFMA(av, wreg[1][ks], acc[1]);                           \
            acc[2] = MFMA(av, wreg[2][ks], acc[2]);                           \
            acc[3] = MFMA(av, wreg[3][ks], acc[3]);                           \
            s16x8 b4 = *(const s16x8*)(&wlds[(((w * 2 + 0) * 8 + ks) * 64 + lane) * 8]); \
            acc[4] = MFMA(av, b4, acc[4]);                                    \
            s16x8 b5 = *(const s16x8*)(&wlds[(((w * 2 + 1) * 8 + ks) * 64 + lane) * 8]); \
            acc[5] = MFMA(av, b5, acc[5]);                                    \
            if constexpr (USE_WS) {                                           \
                acc[6] = MFMA(av, bo[ks & 1][0], acc[6]);                     \
                acc[7] = MFMA(av, bo[ks & 1][1], acc[7]);                     \
                if (ks < 6) {                                                 \
                    bo[ks & 1][0] = *(const s16x8*)(wsb + 0 * 8192 + (ks + 2) * 1024); \
                    bo[ks & 1][1] = *(const s16x8*)(wsb + 1 * 8192 + (ks + 2) * 1024); \
                }                                                             \
            } else {                                                          \
                acc[6] = MFMA(av, wregO[0][ks], acc[6]);                      \
                acc[7] = MFMA(av, wregO[1][ks], acc[7]);                      \
            }                                                                 \
        }                                                                     \
        _Pragma("unroll")                                                     \
        for (int ct = 0; ct < 2; ++ct) {                                      \
            _Pragma("unroll")                                                 \
            for (int r = 0; r < 4; ++r) {                                     \
                float zi = acc[0 + ct][r] + bf2f(XGC[0 + ct][r]);             \
                float zf = acc[2 + ct][r] + bf2f(XGC[2 + ct][r]);             \
                float zg = acc[4 + ct][r] + bf2f(XGC[4 + ct][r]);             \
                float zo = acc[6 + ct][r] + bf2f(XGC[6 + ct][r]);             \
                float Ei = e2c(-C1 * zi);                                     \
                float Ef = e2c(-C1 * zf);                                     \
                float Eg = e2c(-C2 * zg);                                     \
                float Eo = e2c(-C1 * zo);                                     \
                float ai = 1.0f + Ei, af = 1.0f + Ef;                         \
                float ag = 1.0f + Eg, ao = 1.0f + Eo;                         \
                float r1 = __builtin_amdgcn_rcpf(ai * af);                    \
                float gi = r1 * af;                                           \
                float gf = r1 * ai;                                           \
                float r2 = __builtin_amdgcn_rcpf(ag * ao);                    \
                float go = r2 * ag;                                           \
                float tg = 2.0f * (r2 * ao) - 1.0f;                           \
                float c  = gf * cst[ct][r] + gi * tg;                         \
                cst[ct][r] = c;                                               \
                float Ec = e2c(-C2 * c);                                      \
                float tc = 2.0f * __builtin_amdgcn_rcpf(1.0f + Ec) - 1.0f;    \
                hnew[ct][r] = go * tc;                                        \
            }                                                                 \
        }                                                                     \
        /* h -> hlds[PAR^1] (other buffer: no pre-write barrier needed) */    \
        _Pragma("unroll")                                                     \
        for (int ct = 0; ct < 2; ++ct)                                        \
            _Pragma("unroll")                                                 \
            for (int r = 0; r < 4; ++r) {                                     \
                int row = kg * 4 + r;                                         \
                int col = 32 * w + 16 * ct + l15;                             \
                int byte = row * 512 + ((2 * col) ^ ((row & 7) << 4));        \
                *(short*)((char*)hlds[(PAR) ^ 1] + byte) = f2bf(hnew[ct][r]); \
            }                                                                 \
        /* single barrier: vmcnt(0) = my prefetch loads done (stores from */  \
        /* step T-1 had a full step to retire); lgkm = hlds visible */        \
        asm volatile("s_waitcnt vmcnt(0)" ::: "memory");                      \
        asm volatile("s_waitcnt lgkmcnt(0)" ::: "memory");                    \
        __builtin_amdgcn_s_barrier();                                         \
        asm volatile("" ::: "memory");                                        \
    } while (0)

#pragma unroll 1
    for (int tt = 0; tt < T_N; tt += 2) {
        STEP(xgA, xgB, 0, tt);
        STEP(xgB, xgA, 1, tt + 1);
    }

    // epilogue: h,c of last step + final (hy[-1], cy[-1])
    {
        char* hp = st_h + ((size_t)(T_N - 1) << 16);
        char* cp = st_c + ((size_t)(T_N - 1) << 16);
        char* fh = out + 2 * HY_BYTES + (size_t)(g * 16 + kg * 4) * 1024 + (size_t)(32 * w + l15) * 4;
        char* fc = fh + 65536;
#pragma unroll
        for (int ct = 0; ct < 2; ++ct)
#pragma unroll
            for (int r = 0; r < 4; ++r) {
                *(float*)(hp + r * 1024 + ct * 64) = hnew[ct][r];
                *(float*)(cp + r * 1024 + ct * 64) = cst[ct][r];
                *(float*)(fh + r * 1024 + ct * 64) = hnew[ct][r];
                *(float*)(fc + r * 1024 + ct * 64) = cst[ct][r];
            }
    }
#undef STEP
#undef XG_LOAD
}

extern "C" void kernel_launch(void* const* d_in, const int* in_sizes, int n_in,
                              void* d_out, int out_size, void* d_ws, size_t ws_size,
                              hipStream_t stream) {
    (void)in_sizes; (void)n_in; (void)out_size;
    const float* x    = (const float*)d_in[0];
    const float* h0   = (const float*)d_in[1];
    const float* c0   = (const float*)d_in[2];
    const float* w_ih = (const float*)d_in[3];
    const float* w_hh = (const float*)d_in[4];
    const float* b_ih = (const float*)d_in[5];
    const float* b_hh = (const float*)d_in[6];
    char* out = (char*)d_out;

    xg_gemm<<<dim3(1024, 4), 512, 0, stream>>>(x, w_ih, b_ih, b_hh, out);
    if (ws_size >= 131072) {
        lstm_rec<true><<<4, 512, 0, stream>>>(h0, c0, w_hh, out, (char*)d_ws);
    } else {
        lstm_rec<false><<<4, 512, 0, stream>>>(h0, c0, w_hh, out, (char*)d_ws);
    }
}

// Round 4
// 9817.854 us; speedup vs baseline: 1.6664x; 1.2180x over previous
//
#include <hip/hip_runtime.h>

typedef short s16x8 __attribute__((ext_vector_type(8)));
typedef short s16x4 __attribute__((ext_vector_type(4)));
typedef float f32x4 __attribute__((ext_vector_type(4)));

#define T_N 2048
#define B_N 64
#define H_N 256
#define I_N 256
#define HY_BYTES ((size_t)134217728)   // 4 * T * B * H

static __device__ __forceinline__ short f2bf(float f) {
    unsigned u = __builtin_bit_cast(unsigned, f);
    u += 0x7FFFu + ((u >> 16) & 1u);   // RNE
    return (short)(u >> 16);
}
static __device__ __forceinline__ float bf2f(short h) {
    unsigned u = ((unsigned)(unsigned short)h) << 16;
    return __builtin_bit_cast(float, u);
}
static __device__ __forceinline__ float e2c(float a) {
    return __builtin_amdgcn_exp2f(fminf(a, 126.0f));
}
static __device__ __forceinline__ s16x4 ntl4(const void* p) {
    return __builtin_nontemporal_load((const s16x4*)p);
}
static __device__ __forceinline__ void ntsf(void* p, float v) {
    __builtin_nontemporal_store(v, (float*)p);
}

#define C1 1.44269504088896340f   // log2(e)
#define C2 2.88539008177792681f   // 2*log2(e)

#define MFMA(a, b, c) __builtin_amdgcn_mfma_f32_16x16x32_bf16(a, b, c, 0, 0, 0)

// ---------------------------------------------------------------------------
// Phase 1: xg[t,b,n] = x[t,b,:] @ w_ih[n,:] + (b_ih[n]+b_hh[n]),  bf16 in
// MFMA C-fragment layout inside d_out (unchanged).
// ---------------------------------------------------------------------------
__global__ __launch_bounds__(512) void xg_gemm(
        const float* __restrict__ x, const float* __restrict__ w_ih,
        const float* __restrict__ b_ih, const float* __restrict__ b_hh,
        char* __restrict__ out)
{
    const int tid  = threadIdx.x;
    const int wave = tid >> 6;
    const int lane = tid & 63;
    const int l15  = lane & 15;
    const int kg   = lane >> 4;

    __shared__ short Blds[8192];

    const int m16 = blockIdx.x * 8 + wave;
    const int by  = blockIdx.y;
    const int n0  = by * 256;

    const float* xrow = x + (size_t)(m16 * 16 + l15) * I_N;

    f32x4 acc[16] = {};

#pragma unroll 1
    for (int ks = 0; ks < 8; ++ks) {
        __syncthreads();
#pragma unroll
        for (int h = 0; h < 2; ++h) {
            int nl = (tid >> 2) + h * 128;
            int c  = tid & 3;
            const float* wp = w_ih + (size_t)(n0 + nl) * I_N + ks * 32 + c * 8;
            f32x4 w0 = *(const f32x4*)(wp);
            f32x4 w1 = *(const f32x4*)(wp + 4);
            s16x8 bv;
            bv[0]=f2bf(w0[0]); bv[1]=f2bf(w0[1]); bv[2]=f2bf(w0[2]); bv[3]=f2bf(w0[3]);
            bv[4]=f2bf(w1[0]); bv[5]=f2bf(w1[1]); bv[6]=f2bf(w1[2]); bv[7]=f2bf(w1[3]);
            int dt = nl >> 4;
            int lp = (nl & 15) + 16 * c;
            *(s16x8*)(&Blds[(dt * 64 + lp) * 8]) = bv;
        }
        __syncthreads();
        const float* ap = xrow + ks * 32 + kg * 8;
        f32x4 a0 = *(const f32x4*)(ap);
        f32x4 a1 = *(const f32x4*)(ap + 4);
        s16x8 av;
        av[0]=f2bf(a0[0]); av[1]=f2bf(a0[1]); av[2]=f2bf(a0[2]); av[3]=f2bf(a0[3]);
        av[4]=f2bf(a1[0]); av[5]=f2bf(a1[1]); av[6]=f2bf(a1[2]); av[7]=f2bf(a1[3]);
#pragma unroll
        for (int dt = 0; dt < 16; ++dt) {
            s16x8 bv = *(const s16x8*)(&Blds[(dt * 64 + lane) * 8]);
            acc[dt] = MFMA(av, bv, acc[dt]);
        }
    }

    const int t = m16 >> 2;
    const int g = m16 & 3;
#pragma unroll
    for (int dt = 0; dt < 16; ++dt) {
        int tau = by * 16 + dt;
        int n   = tau * 16 + l15;
        float bias = b_ih[n] + b_hh[n];
        size_t base = (tau < 32)
            ? ((size_t)t * 65536 + (size_t)g * 16384 + (size_t)tau * 512)
            : (HY_BYTES + (size_t)t * 65536 + (size_t)g * 16384 + (size_t)(tau - 32) * 512);
        s16x4 o;
        o[0] = f2bf(acc[dt][0] + bias);
        o[1] = f2bf(acc[dt][1] + bias);
        o[2] = f2bf(acc[dt][2] + bias);
        o[3] = f2bf(acc[dt][3] + bias);
        *(s16x4*)(out + base + lane * 8) = o;
    }
}

// ---------------------------------------------------------------------------
// Phase 2: persistent recurrence, 4 WGs x 8 waves, one barrier per step.
// VGPR budget pinned to 256/wave (waves_per_eu(2,2)) so W i,f stay resident:
// no spill/remat.  acc is initialized directly from the xg fragment (same
// layout), killing the zero-init + z-add pass and halving xg buffering.
// o-gate weights streamed from ws (L2) with a 3-deep ks ring.
// ---------------------------------------------------------------------------
template<bool USE_WS>
__global__ __launch_bounds__(512)
__attribute__((amdgpu_waves_per_eu(2, 2)))
void lstm_rec(
        const float* __restrict__ h0, const float* __restrict__ c0,
        const float* __restrict__ w_hh, char* __restrict__ out,
        char* __restrict__ ws)
{
    const int g    = blockIdx.x;
    const int tid  = threadIdx.x;
    const int w    = tid >> 6;
    const int lane = tid & 63;
    const int l15  = lane & 15;
    const int kg   = lane >> 4;

    __shared__ short hlds[2][4096];  // double-buffered 16x256 bf16, swizzled (16 KB)
    __shared__ short wlds[65536];    // g-gate weights (128 KB)

    s16x8 wreg[4][8];       // i,f gates in VGPRs (128 VGPR)
    s16x8 wregO[2][8];      // o gates (fallback only; DCE'd when USE_WS)

#pragma unroll
    for (int d = 0; d < 8; ++d) {
        const int q = d >> 1, ct = d & 1;
        const int tau = 16 * q + 2 * w + ct;
        const float* wp = w_hh + (size_t)(tau * 16 + l15) * H_N;
#pragma unroll
        for (int ks = 0; ks < 8; ++ks) {
            const float* p = wp + ks * 32 + kg * 8;
            f32x4 w0 = *(const f32x4*)(p);
            f32x4 w1 = *(const f32x4*)(p + 4);
            s16x8 v;
            v[0]=f2bf(w0[0]); v[1]=f2bf(w0[1]); v[2]=f2bf(w0[2]); v[3]=f2bf(w0[3]);
            v[4]=f2bf(w1[0]); v[5]=f2bf(w1[1]); v[6]=f2bf(w1[2]); v[7]=f2bf(w1[3]);
            if (d < 4) {
                wreg[d][ks] = v;
            } else if (d < 6) {
                *(s16x8*)(&wlds[(((w * 2 + (d - 4)) * 8 + ks) * 64 + lane) * 8]) = v;
            } else {
                if constexpr (USE_WS) {
                    *(s16x8*)(ws + (size_t)(((w * 2 + (d - 6)) * 8 + ks) * 64 + lane) * 16) = v;
                } else {
                    wregO[d - 6][ks] = v;
                }
            }
        }
    }
    if constexpr (USE_WS) {
        asm volatile("s_waitcnt vmcnt(0)" ::: "memory");
    }

    // ---- h0 -> hlds[0] (bf16, XOR swizzle per row) ----
    {
        const int row  = tid >> 5;
        const int col0 = (tid & 31) * 8;
        const float* hp = h0 + (size_t)(g * 16 + row) * H_N + col0;
        const int sw = (row & 7) << 4;
#pragma unroll
        for (int j = 0; j < 8; ++j) {
            int byte = row * 512 + ((2 * (col0 + j)) ^ sw);
            *(short*)((char*)hlds[0] + byte) = f2bf(hp[j]);
        }
    }

    // ---- c0 -> registers ----
    float cst[2][4];
#pragma unroll
    for (int ct = 0; ct < 2; ++ct)
#pragma unroll
        for (int r = 0; r < 4; ++r)
            cst[ct][r] = c0[(size_t)(g * 16 + kg * 4 + r) * H_N + 32 * w + 16 * ct + l15];

    float hnew[2][4] = {};

    __syncthreads();

    const char* pxg  = out + (size_t)g * 16384 + (size_t)w * 1024 + (size_t)lane * 8;
    char* st_h = out + (size_t)(g * 16 + kg * 4) * 1024 + (size_t)(32 * w + l15) * 4;
    char* st_c = st_h + HY_BYTES;
    const char* wsb = ws + (size_t)w * 16384 + (size_t)lane * 16;

    const int amask = (l15 & 7) << 4;

    s16x4 xg[8];

#define XG_LOAD(T) do {                                                       \
        const char* _p = pxg + ((size_t)(T) << 16);                           \
        xg[0] = ntl4(_p);                   xg[1] = ntl4(_p + 512);           \
        xg[2] = ntl4(_p + 8192);            xg[3] = ntl4(_p + 8704);          \
        xg[4] = ntl4(_p + HY_BYTES);        xg[5] = ntl4(_p + HY_BYTES + 512);\
        xg[6] = ntl4(_p + HY_BYTES + 8192); xg[7] = ntl4(_p + HY_BYTES + 8704);\
    } while (0)

    XG_LOAD(0);   // prologue: xg for step 0
    asm volatile("s_waitcnt vmcnt(0)" ::: "memory");

#define STEP(PAR, T) do {                                                     \
        /* h,c of step T-1 -> global (slot T-1; ordered by prior barriers) */ \
        if ((T) > 0) {                                                        \
            char* _hp = st_h + ((size_t)((T) - 1) << 16);                     \
            char* _cp = st_c + ((size_t)((T) - 1) << 16);                     \
            _Pragma("unroll")                                                 \
            for (int ct = 0; ct < 2; ++ct)                                    \
                _Pragma("unroll")                                             \
                for (int r = 0; r < 4; ++r) {                                 \
                    ntsf(_hp + r * 1024 + ct * 64, hnew[ct][r]);              \
                    ntsf(_cp + r * 1024 + ct * 64, cst[ct][r]);               \
                }                                                             \
        }                                                                     \
        /* acc <- xg fragment (identical layout); xg regs then retire */      \
        f32x4 acc[8];                                                         \
        _Pragma("unroll")                                                     \
        for (int d = 0; d < 8; ++d) {                                         \
            acc[d][0] = bf2f(xg[d][0]); acc[d][1] = bf2f(xg[d][1]);           \
            acc[d][2] = bf2f(xg[d][2]); acc[d][3] = bf2f(xg[d][3]);           \
        }                                                                     \
        /* prefetch next step's xg into the (now free) same regs */           \
        if ((T) + 1 < T_N) XG_LOAD((T) + 1);                                  \
        s16x8 bo0, bo1, bo2, bo3, bo4, bo5;                                   \
        if constexpr (USE_WS) {                                               \
            bo0 = *(const s16x8*)(wsb + 0 * 8192 + 0 * 1024);                 \
            bo1 = *(const s16x8*)(wsb + 1 * 8192 + 0 * 1024);                 \
            bo2 = *(const s16x8*)(wsb + 0 * 8192 + 1 * 1024);                 \
            bo3 = *(const s16x8*)(wsb + 1 * 8192 + 1 * 1024);                 \
            bo4 = *(const s16x8*)(wsb + 0 * 8192 + 2 * 1024);                 \
            bo5 = *(const s16x8*)(wsb + 1 * 8192 + 2 * 1024);                 \
        }                                                                     \
        _Pragma("unroll")                                                     \
        for (int ks = 0; ks < 8; ++ks) {                                      \
            s16x8 av = *(const s16x8*)((const char*)hlds[PAR] +               \
                            l15 * 512 + ((ks * 64 + kg * 16) ^ amask));       \
            acc[0] = MFMA(av, wreg[0][ks], acc[0]);                           \
            acc[1] = MFMA(av, wreg[1][ks], acc[1]);                           \
            acc[2] = MFMA(av, wreg[2][ks], acc[2]);                           \
            acc[3] = MFMA(av, wreg[3][ks], acc[3]);                           \
            s16x8 b4 = *(const s16x8*)(&wlds[(((w * 2 + 0) * 8 + ks) * 64 + lane) * 8]); \
            acc[4] = MFMA(av, b4, acc[4]);                                    \
            s16x8 b5 = *(const s16x8*)(&wlds[(((w * 2 + 1) * 8 + ks) * 64 + lane) * 8]); \
            acc[5] = MFMA(av, b5, acc[5]);                                    \
            if constexpr (USE_WS) {                                           \
                s16x8 c0r, c1r;                                               \
                if ((ks % 3) == 0)      { c0r = bo0; c1r = bo1; }             \
                else if ((ks % 3) == 1) { c0r = bo2; c1r = bo3; }             \
                else                    { c0r = bo4; c1r = bo5; }             \
                acc[6] = MFMA(av, c0r, acc[6]);                               \
                acc[7] = MFMA(av, c1r, acc[7]);                               \
                if (ks < 5) {                                                 \
                    s16x8 n0 = *(const s16x8*)(wsb + 0 * 8192 + (ks + 3) * 1024); \
                    s16x8 n1 = *(const s16x8*)(wsb + 1 * 8192 + (ks + 3) * 1024); \
                    if ((ks % 3) == 0)      { bo0 = n0; bo1 = n1; }           \
                    else if ((ks % 3) == 1) { bo2 = n0; bo3 = n1; }           \
                    else                    { bo4 = n0; bo5 = n1; }           \
                }                                                             \
            } else {                                                          \
                acc[6] = MFMA(av, wregO[0][ks], acc[6]);                      \
                acc[7] = MFMA(av, wregO[1][ks], acc[7]);                      \
            }                                                                 \
        }                                                                     \
        _Pragma("unroll")                                                     \
        for (int ct = 0; ct < 2; ++ct) {                                      \
            _Pragma("unroll")                                                 \
            for (int r = 0; r < 4; ++r) {                                     \
                float zi = acc[0 + ct][r];                                    \
                float zf = acc[2 + ct][r];                                    \
                float zg = acc[4 + ct][r];                                    \
                float zo = acc[6 + ct][r];                                    \
                float Ei = e2c(-C1 * zi);                                     \
                float Ef = e2c(-C1 * zf);                                     \
                float Eg = e2c(-C2 * zg);                                     \
                float Eo = e2c(-C1 * zo);                                     \
                float ai = 1.0f + Ei, af = 1.0f + Ef;                         \
                float ag = 1.0f + Eg, ao = 1.0f + Eo;                         \
                float r1 = __builtin_amdgcn_rcpf(ai * af);                    \
                float gi = r1 * af;                                           \
                float gf = r1 * ai;                                           \
                float r2 = __builtin_amdgcn_rcpf(ag * ao);                    \
                float go = r2 * ag;                                           \
                float tg = 2.0f * (r2 * ao) - 1.0f;                           \
                float c  = gf * cst[ct][r] + gi * tg;                         \
                cst[ct][r] = c;                                               \
                float Ec = e2c(-C2 * c);                                      \
                float tc = 2.0f * __builtin_amdgcn_rcpf(1.0f + Ec) - 1.0f;    \
                hnew[ct][r] = go * tc;                                        \
            }                                                                 \
        }                                                                     \
        /* h -> hlds[PAR^1] (other buffer: no pre-write barrier needed) */    \
        _Pragma("unroll")                                                     \
        for (int ct = 0; ct < 2; ++ct)                                        \
            _Pragma("unroll")                                                 \
            for (int r = 0; r < 4; ++r) {                                     \
                int row = kg * 4 + r;                                         \
                int col = 32 * w + 16 * ct + l15;                             \
                int byte = row * 512 + ((2 * col) ^ ((row & 7) << 4));        \
                *(short*)((char*)hlds[(PAR) ^ 1] + byte) = f2bf(hnew[ct][r]); \
            }                                                                 \
        /* single barrier: vmcnt(0) = xg prefetch done (h/c stores had a */   \
        /* full step to retire); lgkm = hlds visible */                       \
        asm volatile("s_waitcnt vmcnt(0)" ::: "memory");                      \
        asm volatile("s_waitcnt lgkmcnt(0)" ::: "memory");                    \
        __builtin_amdgcn_s_barrier();                                         \
        asm volatile("" ::: "memory");                                        \
    } while (0)

#pragma unroll 1
    for (int tt = 0; tt < T_N; tt += 2) {
        STEP(0, tt);
        STEP(1, tt + 1);
    }

    // epilogue: h,c of last step + final (hy[-1], cy[-1])
    {
        char* hp = st_h + ((size_t)(T_N - 1) << 16);
        char* cp = st_c + ((size_t)(T_N - 1) << 16);
        char* fh = out + 2 * HY_BYTES + (size_t)(g * 16 + kg * 4) * 1024 + (size_t)(32 * w + l15) * 4;
        char* fc = fh + 65536;
#pragma unroll
        for (int ct = 0; ct < 2; ++ct)
#pragma unroll
            for (int r = 0; r < 4; ++r) {
                *(float*)(hp + r * 1024 + ct * 64) = hnew[ct][r];
                *(float*)(cp + r * 1024 + ct * 64) = cst[ct][r];
                *(float*)(fh + r * 1024 + ct * 64) = hnew[ct][r];
                *(float*)(fc + r * 1024 + ct * 64) = cst[ct][r];
            }
    }
#undef STEP
#undef XG_LOAD
}

extern "C" void kernel_launch(void* const* d_in, const int* in_sizes, int n_in,
                              void* d_out, int out_size, void* d_ws, size_t ws_size,
                              hipStream_t stream) {
    (void)in_sizes; (void)n_in; (void)out_size;
    const float* x    = (const float*)d_in[0];
    const float* h0   = (const float*)d_in[1];
    const float* c0   = (const float*)d_in[2];
    const float* w_ih = (const float*)d_in[3];
    const float* w_hh = (const float*)d_in[4];
    const float* b_ih = (const float*)d_in[5];
    const float* b_hh = (const float*)d_in[6];
    char* out = (char*)d_out;

    xg_gemm<<<dim3(1024, 4), 512, 0, stream>>>(x, w_ih, b_ih, b_hh, out);
    if (ws_size >= 131072) {
        lstm_rec<true><<<4, 512, 0, stream>>>(h0, c0, w_hh, out, (char*)d_ws);
    } else {
        lstm_rec<false><<<4, 512, 0, stream>>>(h0, c0, w_hh, out, (char*)d_ws);
    }
}